// Round 3
// baseline (14551.047 us; speedup 1.0000x reference)
//
#include <hip/hip_runtime.h>

// 6-layer GRU, T=512, B=256, I=128, H=256. ALL I/O IS FLOAT32 (reference dtype;
// the 2%-of-max threshold and round-0/1 NaN forensics confirm). MFMA operands
// are converted f32->bf16 on the fly; h carried in f32; internal gx ws is bf16.
// d_out = [cur 512*256*256][finals 6*256*256] f32.
//
// Per layer, per T-chunk(Tc):
//  1) gx_gemm: gx = X @ W_ih^T + b_ih (+b_hh folded for r,z), MFMA bf16 from
//     f32-staged LDS slabs, output bf16 in scan layout [t][b>>4][g(768)][b&15].
//  2) gru_scan: 16 WGs x 512 thr, weight-stationary (W_hh bf16 fragments
//     resident in VGPRs, 192 regs/lane), h f32 in regs, bf16 h via
//     double-buffered swizzled LDS, 1 barrier/step, gx prefetch 1 step ahead.
// Layer chaining IN-PLACE through d_out; ws = gx (Tc*16*768*16*2 B) + hcar.

#define NLAY 6

typedef __bf16 bf16x8 __attribute__((ext_vector_type(8)));
typedef float  f32x4  __attribute__((ext_vector_type(4)));

typedef const unsigned int __attribute__((address_space(1)))* gp1_t;
typedef unsigned int __attribute__((address_space(3)))* lp3_t;

__device__ __forceinline__ float b2f(unsigned short u) {
  union { unsigned int i; float f; } v; v.i = ((unsigned int)u) << 16; return v.f;
}
__device__ __forceinline__ unsigned short f2bs(float f) {
  union { __bf16 b; unsigned short s; } v; v.b = (__bf16)f; return v.s;
}
__device__ __forceinline__ bf16x8 cvt8(f32x4 lo, f32x4 hi) {
  bf16x8 r;
#pragma unroll
  for (int i = 0; i < 4; ++i) { r[i] = (__bf16)lo[i]; r[4 + i] = (__bf16)hi[i]; }
  return r;
}

// ---------------------------------------------------------------------------
// gx[m,g] = sum_k X[m,k]*W[g,k] + bias(g);  m = t*256+b (chunk-local t)
// X: [M][K] f32 row-major, W: [768][K] f32 row-major, K in {128,256}.
// GX (bf16): (t,b,g) -> GX[((t*16 + (b>>4))*768 + g)*16 + (b&15)]
// grid = (M/128, 6), block = 256. LDS slabs [128 rows][32 k] f32, 8 16B-groups
// per row; physical group g holds logical group g ^ (row&7).
// ---------------------------------------------------------------------------
__global__ __launch_bounds__(256) void gx_gemm(
    const float* __restrict__ X,
    const float* __restrict__ W,
    const float* __restrict__ bih,
    const float* __restrict__ bhh,
    unsigned short* __restrict__ GX,
    int K)
{
  __shared__ __align__(16) float Asf[128 * 32];
  __shared__ __align__(16) float Bsf[128 * 32];
  const int tid  = threadIdx.x;
  const int lane = tid & 63;
  const int w    = tid >> 6;           // wave 0..3
  const int wy   = w >> 1, wx = w & 1; // 2x2 wave grid, 64x64 per wave
  const int l15  = lane & 15, q = lane >> 4;
  const int m0   = blockIdx.x * 128;
  const int n0   = blockIdx.y * 128;

  f32x4 acc[4][4];
#pragma unroll
  for (int a = 0; a < 4; ++a)
#pragma unroll
    for (int b = 0; b < 4; ++b) acc[a][b] = f32x4{0.f, 0.f, 0.f, 0.f};

  const int kiters = K >> 5;
  for (int kt = 0; kt < kiters; ++kt) {
    // stage: 1024 16B-chunks per slab (128 rows x 8 groups of 4 floats)
#pragma unroll
    for (int i = 0; i < 4; ++i) {
      int ci  = (w * 4 + i) * 64 + lane;   // 0..1023
      int row = ci >> 3;
      int g   = ci & 7;
      int kg  = g ^ (row & 7);
      const float* srcA = X + (size_t)(m0 + row) * K + kt * 32 + kg * 4;
      const float* srcB = W + (size_t)(n0 + row) * K + kt * 32 + kg * 4;
      __builtin_amdgcn_global_load_lds((gp1_t)(const void*)srcA,
          (lp3_t)(void*)((char*)Asf + (w * 4 + i) * 1024), 16, 0, 0);
      __builtin_amdgcn_global_load_lds((gp1_t)(const void*)srcB,
          (lp3_t)(void*)((char*)Bsf + (w * 4 + i) * 1024), 16, 0, 0);
    }
    __syncthreads();

    bf16x8 a[4], b[4];
#pragma unroll
    for (int tm = 0; tm < 4; ++tm) {
      int row = wy * 64 + tm * 16 + l15;
      int p0  = (2 * q) ^ (row & 7);
      int p1  = (2 * q + 1) ^ (row & 7);
      f32x4 lo = *(const f32x4*)(Asf + row * 32 + p0 * 4);
      f32x4 hi = *(const f32x4*)(Asf + row * 32 + p1 * 4);
      a[tm] = cvt8(lo, hi);
    }
#pragma unroll
    for (int tn = 0; tn < 4; ++tn) {
      int row = wx * 64 + tn * 16 + l15;
      int p0  = (2 * q) ^ (row & 7);
      int p1  = (2 * q + 1) ^ (row & 7);
      f32x4 lo = *(const f32x4*)(Bsf + row * 32 + p0 * 4);
      f32x4 hi = *(const f32x4*)(Bsf + row * 32 + p1 * 4);
      b[tn] = cvt8(lo, hi);
    }
#pragma unroll
    for (int tm = 0; tm < 4; ++tm)
#pragma unroll
      for (int tn = 0; tn < 4; ++tn)
        acc[tm][tn] = __builtin_amdgcn_mfma_f32_16x16x32_bf16(a[tm], b[tn], acc[tm][tn], 0, 0, 0);
    __syncthreads();
  }

  // epilogue: bias add (+b_hh folded for gates r,z i.e. g<512), bf16, permuted
#pragma unroll
  for (int tn = 0; tn < 4; ++tn) {
    int g = n0 + wx * 64 + tn * 16 + l15;
    float bias = bih[g] + (g < 512 ? bhh[g] : 0.f);
#pragma unroll
    for (int tm = 0; tm < 4; ++tm) {
#pragma unroll
      for (int r = 0; r < 4; ++r) {
        int m = m0 + wy * 64 + tm * 16 + q * 4 + r;  // C row = 4*q + r
        int t = m >> 8, bb = m & 255;
        size_t dst = ((size_t)(t * 16 + (bb >> 4)) * 768 + g) * 16 + (bb & 15);
        GX[dst] = f2bs(acc[tm][tn][r] + bias);
      }
    }
  }
}

// ---------------------------------------------------------------------------
// Recurrent scan. One WG per 16 batch rows (16 WGs, no inter-WG comm).
// 8 waves; wave w owns gh columns [32w,32w+32) for all 3 gates (6 MFMA
// N-tiles). W_hh bf16 B-fragments resident in VGPRs. h in f32 regs (lane:
// rows 4q+r, cols jb+16c); bf16 h in double-buffered swizzled LDS (A-op).
// ---------------------------------------------------------------------------
__global__ __launch_bounds__(512, 2) void gru_scan(
    const unsigned short* __restrict__ GX,    // [Tc][16][768][16] bf16
    const float* __restrict__ Whh,            // [768][256] f32 layer base
    const float* __restrict__ bhh,            // [768] f32 (n-part used)
    float* __restrict__ hcar,                 // [256][256] f32 carry
    const float* __restrict__ h0,             // [256][256] f32 layer slice
    float* __restrict__ Y,                    // chunk out [Tc][256][256] f32
    float* __restrict__ FIN,                  // finals slice f32 or nullptr
    int Tc, int first)
{
  __shared__ __align__(16) unsigned short hl[2][16 * 256];  // bf16 h, dbuf, swizzled
  const int wg  = blockIdx.x;
  const int b0  = wg << 4;
  const int tid = threadIdx.x;
  const int lane = tid & 63;
  const int w  = tid >> 6;       // 0..7
  const int m  = lane & 15;
  const int q  = lane >> 4;
  const int jb = w * 32 + m;     // j col base (c adds 16)

  // resident W_hh B-fragments: B[k][n], n(lane&15)=W row, k = kt*32+8q+i
  bf16x8 bw[6][8];
#pragma unroll
  for (int gate = 0; gate < 3; ++gate)
#pragma unroll
    for (int c = 0; c < 2; ++c) {
      int n = gate * 256 + jb + c * 16;
#pragma unroll
      for (int kt = 0; kt < 8; ++kt) {
        f32x4 lo = *(const f32x4*)(Whh + (size_t)n * 256 + kt * 32 + q * 8);
        f32x4 hi = *(const f32x4*)(Whh + (size_t)n * 256 + kt * 32 + q * 8 + 4);
        bw[gate * 2 + c][kt] = cvt8(lo, hi);
      }
    }

  float bhn[2];
#pragma unroll
  for (int c = 0; c < 2; ++c) bhn[c] = bhh[512 + jb + c * 16];

  // h registers: rows b0+4q+r, cols jb+16c
  float h[2][4];
#pragma unroll
  for (int c = 0; c < 2; ++c)
#pragma unroll
    for (int r = 0; r < 4; ++r) {
      int bb = b0 + q * 4 + r;
      int j  = jb + c * 16;
      h[c][r] = first ? h0[bb * 256 + j] : hcar[bb * 256 + j];
    }

  // init LDS buf 0 (swizzle: addr = b*256 + (((j>>3)^(b&7))<<3) + (j&7))
#pragma unroll
  for (int c = 0; c < 2; ++c)
#pragma unroll
    for (int r = 0; r < 4; ++r) {
      int bb = q * 4 + r;
      int j  = jb + c * 16;
      int ad = bb * 256 + ((((j >> 3) ^ (bb & 7))) << 3) + (j & 7);
      hl[0][ad] = f2bs(h[c][r]);
    }

  // gx prefetch for t=0 (rows 4q..4q+3 at col g, 8B coalesced)
  const unsigned short* g0 = GX + ((size_t)wg * 768 + jb) * 16 + q * 4;
  ushort4 pf[6];
  pf[0] = *(const ushort4*)(g0);                // gate0, c=0
  pf[1] = *(const ushort4*)(g0 + 256);          // gate0, c=1
  pf[2] = *(const ushort4*)(g0 + 4096);         // gate1, c=0
  pf[3] = *(const ushort4*)(g0 + 4096 + 256);   // gate1, c=1
  pf[4] = *(const ushort4*)(g0 + 8192);         // gate2, c=0
  pf[5] = *(const ushort4*)(g0 + 8192 + 256);   // gate2, c=1

  float* yp = Y + (size_t)(b0 + q * 4) * 256 + jb;
  __syncthreads();

  for (int t = 0; t < Tc; ++t) {
    // ---- gh = bf16(h) @ W_hh^T  (A from LDS, B resident in VGPRs) ----
    f32x4 acc[6];
#pragma unroll
    for (int i = 0; i < 6; ++i) acc[i] = f32x4{0.f, 0.f, 0.f, 0.f};
    const unsigned short* hb = hl[t & 1];
#pragma unroll
    for (int kt = 0; kt < 8; ++kt) {
      int ad = m * 256 + (((kt * 4 + q) ^ (m & 7)) << 3);
      bf16x8 af = *(const bf16x8*)(hb + ad);
#pragma unroll
      for (int i = 0; i < 6; ++i)
        acc[i] = __builtin_amdgcn_mfma_f32_16x16x32_bf16(af, bw[i][kt], acc[i], 0, 0, 0);
    }

    // ---- pointwise GRU cell (f32), write next-h to other LDS buffer ----
    unsigned short* hw = hl[(t + 1) & 1];
#pragma unroll
    for (int c = 0; c < 2; ++c) {
      ushort4 pr4 = pf[c];          // i_r (+b_ih+b_hh)
      ushort4 pz4 = pf[2 + c];      // i_z (+b_ih+b_hh)
      ushort4 pn4 = pf[4 + c];      // i_n (+b_ih)
#pragma unroll
      for (int r = 0; r < 4; ++r) {
        unsigned short pru = (r == 0) ? pr4.x : (r == 1) ? pr4.y : (r == 2) ? pr4.z : pr4.w;
        unsigned short pzu = (r == 0) ? pz4.x : (r == 1) ? pz4.y : (r == 2) ? pz4.z : pz4.w;
        unsigned short pnu = (r == 0) ? pn4.x : (r == 1) ? pn4.y : (r == 2) ? pn4.z : pn4.w;
        float ir  = b2f(pru);
        float iz  = b2f(pzu);
        float inn = b2f(pnu);
        float rr = 1.f / (1.f + __expf(-(ir + acc[c][r])));
        float zz = 1.f / (1.f + __expf(-(iz + acc[2 + c][r])));
        float nx = inn + rr * (acc[4 + c][r] + bhn[c]);
        float e2 = __expf(2.f * nx);
        float nn = 1.f - 2.f / (e2 + 1.f);      // tanh(nx)
        float hv = nn + zz * (h[c][r] - nn);    // (1-z)*n + z*h
        h[c][r] = hv;
        int bb = q * 4 + r;
        int j  = jb + c * 16;
        int ad = bb * 256 + ((((j >> 3) ^ (bb & 7))) << 3) + (j & 7);
        hw[ad] = f2bs(hv);
        yp[r * 256 + c * 16] = hv;
      }
    }

    // ---- prefetch gx(t+1) into pf (lands during next MFMA phase) ----
    if (t + 1 < Tc) {
      g0 += 196608;                              // 16*768*16 elems per step
      pf[0] = *(const ushort4*)(g0);
      pf[1] = *(const ushort4*)(g0 + 256);
      pf[2] = *(const ushort4*)(g0 + 4096);
      pf[3] = *(const ushort4*)(g0 + 4096 + 256);
      pf[4] = *(const ushort4*)(g0 + 8192);
      pf[5] = *(const ushort4*)(g0 + 8192 + 256);
    }
    yp += 65536;
    __syncthreads();
  }

  // carry out (f32) or finals (f32)
#pragma unroll
  for (int c = 0; c < 2; ++c)
#pragma unroll
    for (int r = 0; r < 4; ++r) {
      int bb = b0 + q * 4 + r;
      int j  = jb + c * 16;
      if (FIN) FIN[bb * 256 + j] = h[c][r];
      else     hcar[bb * 256 + j] = h[c][r];
    }
}

// ---------------------------------------------------------------------------
extern "C" void kernel_launch(void* const* d_in, const int* in_sizes, int n_in,
                              void* d_out, int out_size, void* d_ws, size_t ws_size,
                              hipStream_t stream) {
  const float* x    = (const float*)d_in[0]; // [512][256][128]
  const float* h0   = (const float*)d_in[1]; // [6][256][256]
  const float* Wih0 = (const float*)d_in[2]; // [768][128]
  const float* Wih  = (const float*)d_in[3]; // [5][768][256]
  const float* Whh  = (const float*)d_in[4]; // [6][768][256]
  const float* bih  = (const float*)d_in[5]; // [6][768]
  const float* bhh  = (const float*)d_in[6]; // [6][768]
  float* out = (float*)d_out;

  // largest Tc whose ws fits: gx = Tc*16*768*16*2 B (bf16), + hcar 256KB f32
  int Tc = 128;
  while (Tc > 8) {
    size_t need = (size_t)Tc * 16 * 768 * 16 * 2 + 262144;
    if (need <= ws_size) break;
    Tc >>= 1;
  }
  const int nch = 512 / Tc;
  const size_t gxBytes = (size_t)Tc * 16 * 768 * 16 * 2;

  char* ws = (char*)d_ws;
  unsigned short* gx   = (unsigned short*)ws;
  float*          hcar = (float*)(ws + gxBytes);

  float* cur = out;                              // [512][256][256] f32
  float* fin = out + (size_t)512 * 256 * 256;    // [6][256][256] f32

  for (int l = 0; l < NLAY; ++l) {
    int K = (l == 0) ? 128 : 256;
    const float* Xl = (l == 0) ? x : cur;        // in-place chaining
    const float* Wihl = (l == 0) ? Wih0 : (Wih + (size_t)(l - 1) * 768 * 256);
    const float* Whhl = Whh + (size_t)l * 768 * 256;
    const float* bihl = bih + l * 768;
    const float* bhhl = bhh + l * 768;
    const float* h0l  = h0 + (size_t)l * 65536;

    for (int c = 0; c < nch; ++c) {
      const float* Xc = Xl + (size_t)c * Tc * 256 * K;
      gx_gemm<<<dim3(Tc * 2, 6), 256, 0, stream>>>(Xc, Wihl, bihl, bhhl, gx, K);
      gru_scan<<<dim3(16), dim3(512), 0, stream>>>(
          gx, Whhl, bhhl, hcar, h0l,
          cur + (size_t)c * Tc * 65536,
          (c == nch - 1) ? (fin + (size_t)l * 65536) : (float*)nullptr,
          Tc, c == 0 ? 1 : 0);
    }
  }
  (void)in_sizes; (void)n_in; (void)out_size; (void)ws_size;
}